// Round 1
// baseline (504.717 us; speedup 1.0000x reference)
//
#include <hip/hip_runtime.h>

// PatchMatch brute-force NN: s,t (4,16,64,64) fp32, patch 3x3 replicate-pad.
// Descriptor dim K = 16*9 = 144. Per batch: 4096 queries vs 4096 targets.
// d2(i,j) = qn_i - 2*cross(i,j) + pn_j, argmin_j per i (ties -> smallest j).
// Outputs (concat flat, ALL WRITTEN AS FLOAT32):
//   nnf (4,2,64,64): ch0 = idy, ch1 = idx_x   [32768 elems]
//   nnd (4,1,64,64): min squared distance     [16384 elems]

#define N_  4
#define C_  16
#define H_  64
#define W_  64
#define HW_ 4096

__device__ __forceinline__ int iclamp(int v, int lo, int hi) {
    return v < lo ? lo : (v > hi ? hi : v);
}

__global__ __launch_bounds__(256, 1)
void patchmatch_nn_kernel(const float* __restrict__ s,
                          const float* __restrict__ t,
                          float* __restrict__ out) {
    const int yq  = blockIdx.x;   // query row
    const int n   = blockIdx.y;   // batch
    const int tid = threadIdx.x;
    const int tx  = tid & 15;     // target-group id (16)
    const int ty  = tid >> 4;     // query-group id (16)
    const int i0  = ty * 4;       // 4 queries per thread (x within row yq)
    const int jrow = tx >> 3;     // which of the 2 target rows in the j-tile
    const int jx0  = (tx & 7) * 8; // 8 targets per thread (x within row)

    // Padded x in [-1,64] stored at [0..65]; stride 68 floats = 272 B (16B-mult)
    __shared__ float qS[C_][3][68];   // query row yq: rows clamp(yq-1..yq+1)
    __shared__ float tS[C_][4][68];   // j-tile: rows clamp(2*yt-1 .. 2*yt+2)
    __shared__ float pnS[HW_];        // ||p_j||^2 for all targets
    __shared__ float qnS[W_];         // ||q_i||^2 for this query row

    const float* sb = s + n * (C_ * HW_);
    const float* tb = t + n * (C_ * HW_);

    // ---- pn for ALL targets (each thread does 16) -------------------------
    for (int jj = tid; jj < HW_; jj += 256) {
        const int y = jj >> 6, x = jj & 63;
        float acc = 0.f;
        for (int c = 0; c < C_; ++c) {
            const float* tc = tb + c * HW_;
            #pragma unroll
            for (int dy = 0; dy < 3; ++dy) {
                const float* tr = tc + iclamp(y + dy - 1, 0, H_ - 1) * W_;
                #pragma unroll
                for (int dx = 0; dx < 3; ++dx) {
                    float v = tr[iclamp(x + dx - 1, 0, W_ - 1)];
                    acc += v * v;
                }
            }
        }
        pnS[jj] = acc;
    }

    // ---- stage qS (16c x 3 rows x 66 padded cols) -------------------------
    for (int idx = tid; idx < C_ * 3 * 66; idx += 256) {
        const int c   = idx / (3 * 66);
        const int rem = idx - c * (3 * 66);
        const int rr  = rem / 66;
        const int xi  = rem - rr * 66;
        const int gr  = iclamp(yq + rr - 1, 0, H_ - 1);
        const int gx  = iclamp(xi - 1, 0, W_ - 1);
        qS[c][rr][xi] = sb[c * HW_ + gr * W_ + gx];
    }
    __syncthreads();

    // ---- qn for the 64 queries of this row --------------------------------
    if (tid < W_) {
        float acc = 0.f;
        for (int c = 0; c < C_; ++c)
            #pragma unroll
            for (int dy = 0; dy < 3; ++dy)
                #pragma unroll
                for (int dx = 0; dx < 3; ++dx) {
                    float v = qS[c][dy][tid + dx];
                    acc += v * v;
                }
        qnS[tid] = acc;
    }

    // running best per query, packed (f32_bits << 32) | j  (d2 >= 0 so the
    // unsigned compare is monotone in d2; ties pick smallest j = np argmin)
    unsigned long long best[4] = {~0ull, ~0ull, ~0ull, ~0ull};

    for (int yt = 0; yt < 32; ++yt) {          // 32 j-tiles of 128 targets
        __syncthreads();                        // protect tS readers
        for (int idx = tid; idx < C_ * 4 * 66; idx += 256) {
            const int c   = idx / (4 * 66);
            const int rem = idx - c * (4 * 66);
            const int rr  = rem / 66;
            const int xi  = rem - rr * 66;
            const int gr  = iclamp(2 * yt + rr - 1, 0, H_ - 1);
            const int gx  = iclamp(xi - 1, 0, W_ - 1);
            tS[c][rr][xi] = tb[c * HW_ + gr * W_ + gx];
        }
        __syncthreads();

        float acc[4][8];
        #pragma unroll
        for (int a = 0; a < 4; ++a)
            #pragma unroll
            for (int b = 0; b < 8; ++b) acc[a][b] = 0.f;

        for (int c = 0; c < C_; ++c) {
            #pragma unroll
            for (int dy = 0; dy < 3; ++dy) {
                float qv[8], tv[12];
                *(float4*)&qv[0] = *(const float4*)&qS[c][dy][i0];
                *(float4*)&qv[4] = *(const float4*)&qS[c][dy][i0 + 4];
                const float* trow = &tS[c][jrow + dy][jx0];
                *(float4*)&tv[0] = *(const float4*)&trow[0];
                *(float4*)&tv[4] = *(const float4*)&trow[4];
                *(float4*)&tv[8] = *(const float4*)&trow[8];
                #pragma unroll
                for (int dx = 0; dx < 3; ++dx)
                    #pragma unroll
                    for (int a = 0; a < 4; ++a)
                        #pragma unroll
                        for (int b = 0; b < 8; ++b)
                            acc[a][b] += qv[a + dx] * tv[b + dx];
            }
        }

        // epilogue: d2 = qn + pn - 2*cross, fold into running best
        const int rbase = (2 * yt + jrow) * W_ + jx0;
        #pragma unroll
        for (int a = 0; a < 4; ++a) {
            const float qn = qnS[i0 + a];
            #pragma unroll
            for (int b = 0; b < 8; ++b) {
                const int j = rbase + b;
                const float d2 = qn + pnS[j] - 2.f * acc[a][b];
                unsigned long long cand =
                    ((unsigned long long)__float_as_uint(d2) << 32) | (unsigned)j;
                best[a] = cand < best[a] ? cand : best[a];
            }
        }
    }

    // ---- reduce across the 16 tx lanes sharing each query -----------------
    #pragma unroll
    for (int a = 0; a < 4; ++a) {
        unsigned long long v = best[a];
        #pragma unroll
        for (int m = 8; m >= 1; m >>= 1) {
            unsigned long long o = __shfl_xor(v, m, 64);
            v = o < v ? o : v;
        }
        best[a] = v;
    }

    if (tx == 0) {
        #pragma unroll
        for (int a = 0; a < 4; ++a) {
            const int x   = i0 + a;
            const unsigned j = (unsigned)(best[a] & 0xffffffffu);
            const float d2 = __uint_as_float((unsigned)(best[a] >> 32));
            const int pix = yq * W_ + x;
            out[n * 2 * HW_ + pix]        = (float)(j >> 6);  // idy
            out[n * 2 * HW_ + HW_ + pix]  = (float)(j & 63);  // idx_x
            out[N_ * 2 * HW_ + n * HW_ + pix] = d2;           // nnd
        }
    }
}

extern "C" void kernel_launch(void* const* d_in, const int* in_sizes, int n_in,
                              void* d_out, int out_size, void* d_ws, size_t ws_size,
                              hipStream_t stream) {
    const float* s = (const float*)d_in[0];
    const float* t = (const float*)d_in[1];
    // d_in[2] = patch_size (scalar 3, hardcoded)
    float* out = (float*)d_out;
    dim3 grid(H_, N_);
    patchmatch_nn_kernel<<<grid, 256, 0, stream>>>(s, t, out);
}

// Round 2
// 469.351 us; speedup vs baseline: 1.0754x; 1.0754x over previous
//
#include <hip/hip_runtime.h>

// PatchMatch brute-force NN: s,t (4,16,64,64) fp32, patch 3x3 replicate-pad.
// Descriptor dim K = 16*9 = 144. Per batch: 4096 queries vs 4096 targets.
// d2(i,j) = qn_i - 2*cross(i,j) + pn_j, argmin_j per i (ties -> smallest j).
// Outputs (concat flat, ALL FLOAT32): nnf (4,2,64,64) then nnd (4,1,64,64).
//
// R2: occupancy fix. prep kernel computes pn/qn once into ws; main kernel
// splits j 4-way (grid 64x4x4 = 1024 blocks = 4 blocks/CU, 4 waves/SIMD);
// finalize kernel reduces the 4 partial bests. Fallback to monolithic
// kernel if ws_size < 655360 B.

#define N_  4
#define C_  16
#define H_  64
#define W_  64
#define HW_ 4096
#define SPLITS 4
#define TILES_PER_SPLIT 8     // 32 j-tiles (of 128 targets) / 4 splits

__device__ __forceinline__ int iclamp(int v, int lo, int hi) {
    return v < lo ? lo : (v > hi ? hi : v);
}

// ---------------------------------------------------------------------------
// Kernel 1: pn[n][4096] from t, qn[n][4096] from s  (32768 threads)
// ---------------------------------------------------------------------------
__global__ __launch_bounds__(256)
void prep_norms_kernel(const float* __restrict__ s,
                       const float* __restrict__ t,
                       float* __restrict__ pn,
                       float* __restrict__ qn) {
    const int gid   = blockIdx.x * 256 + threadIdx.x;   // 0..32767
    const int which = gid >> 14;                        // 0 -> pn(t), 1 -> qn(s)
    const int id    = gid & 16383;
    const int n     = id >> 12;
    const int pix   = id & 4095;
    const int y = pix >> 6, x = pix & 63;
    const float* base = (which ? s : t) + n * (C_ * HW_);
    float acc = 0.f;
    for (int c = 0; c < C_; ++c) {
        const float* bc = base + c * HW_;
        #pragma unroll
        for (int dy = 0; dy < 3; ++dy) {
            const float* br = bc + iclamp(y + dy - 1, 0, H_ - 1) * W_;
            #pragma unroll
            for (int dx = 0; dx < 3; ++dx) {
                float v = br[iclamp(x + dx - 1, 0, W_ - 1)];
                acc += v * v;
            }
        }
    }
    (which ? qn : pn)[id] = acc;
}

// ---------------------------------------------------------------------------
// Kernel 2: main cross/argmin over a j-split; partial best -> ws
// ---------------------------------------------------------------------------
__global__ __launch_bounds__(256, 4)
void patchmatch_main_kernel(const float* __restrict__ s,
                            const float* __restrict__ t,
                            const float* __restrict__ pn_g,
                            const float* __restrict__ qn_g,
                            unsigned long long* __restrict__ partial) {
    const int yq    = blockIdx.x;   // query row
    const int n     = blockIdx.y;   // batch
    const int split = blockIdx.z;   // j-split
    const int tid = threadIdx.x;
    const int tx  = tid & 15;
    const int ty  = tid >> 4;
    const int i0  = ty * 4;          // 4 queries per thread
    const int jrow = tx >> 3;        // which of 2 target rows in the j-tile
    const int jx0  = (tx & 7) * 8;   // 8 targets per thread

    __shared__ float qS[C_][3][68];            // 13056 B
    __shared__ float tS[C_][4][68];            // 17408 B
    __shared__ __align__(16) float pnSl[1024]; //  4096 B (this split's targets)
    __shared__ float qnS[W_];                  //   256 B

    const float* sb = s + n * (C_ * HW_);
    const float* tb = t + n * (C_ * HW_);

    // stage qS (16c x 3 rows x 66 padded cols, stride 68)
    for (int idx = tid; idx < C_ * 3 * 66; idx += 256) {
        const int c   = idx / (3 * 66);
        const int rem = idx - c * (3 * 66);
        const int rr  = rem / 66;
        const int xi  = rem - rr * 66;
        qS[c][rr][xi] = sb[c * HW_ + iclamp(yq + rr - 1, 0, H_ - 1) * W_ +
                           iclamp(xi - 1, 0, W_ - 1)];
    }
    // stage this split's pn slice (rows 16*split .. 16*split+15)
    for (int idx = tid; idx < 1024; idx += 256)
        pnSl[idx] = pn_g[n * HW_ + split * 1024 + idx];
    if (tid < W_) qnS[tid] = qn_g[n * HW_ + yq * W_ + tid];

    unsigned long long best[4] = {~0ull, ~0ull, ~0ull, ~0ull};

    for (int ytl = 0; ytl < TILES_PER_SPLIT; ++ytl) {
        const int yt = split * TILES_PER_SPLIT + ytl;
        __syncthreads();                       // qS ready (iter 0) / tS reuse
        for (int idx = tid; idx < C_ * 4 * 66; idx += 256) {
            const int c   = idx / (4 * 66);
            const int rem = idx - c * (4 * 66);
            const int rr  = rem / 66;
            const int xi  = rem - rr * 66;
            tS[c][rr][xi] = tb[c * HW_ + iclamp(2 * yt + rr - 1, 0, H_ - 1) * W_ +
                               iclamp(xi - 1, 0, W_ - 1)];
        }
        __syncthreads();

        float acc[4][8];
        #pragma unroll
        for (int a = 0; a < 4; ++a)
            #pragma unroll
            for (int b = 0; b < 8; ++b) acc[a][b] = 0.f;

        for (int c = 0; c < C_; ++c) {
            #pragma unroll
            for (int dy = 0; dy < 3; ++dy) {
                float qv[8], tv[12];
                *(float4*)&qv[0] = *(const float4*)&qS[c][dy][i0];
                *(float4*)&qv[4] = *(const float4*)&qS[c][dy][i0 + 4];
                const float* trow = &tS[c][jrow + dy][jx0];
                *(float4*)&tv[0] = *(const float4*)&trow[0];
                *(float4*)&tv[4] = *(const float4*)&trow[4];
                *(float4*)&tv[8] = *(const float4*)&trow[8];
                #pragma unroll
                for (int dx = 0; dx < 3; ++dx)
                    #pragma unroll
                    for (int a = 0; a < 4; ++a)
                        #pragma unroll
                        for (int b = 0; b < 8; ++b)
                            acc[a][b] += qv[a + dx] * tv[b + dx];
            }
        }

        // epilogue: d2 = qn + pn - 2*cross
        const int rbl = (2 * ytl + jrow) * W_ + jx0;   // local in pnSl
        float pnv[8];
        *(float4*)&pnv[0] = *(const float4*)&pnSl[rbl];
        *(float4*)&pnv[4] = *(const float4*)&pnSl[rbl + 4];
        const int jbase = split * 1024 + rbl;          // global j
        #pragma unroll
        for (int a = 0; a < 4; ++a) {
            const float qn = qnS[i0 + a];
            #pragma unroll
            for (int b = 0; b < 8; ++b) {
                const float d2 = qn + pnv[b] - 2.f * acc[a][b];
                unsigned long long cand =
                    ((unsigned long long)__float_as_uint(d2) << 32) |
                    (unsigned)(jbase + b);
                best[a] = cand < best[a] ? cand : best[a];
            }
        }
    }

    // reduce across the 16 tx lanes sharing each query
    #pragma unroll
    for (int a = 0; a < 4; ++a) {
        unsigned long long v = best[a];
        #pragma unroll
        for (int m = 8; m >= 1; m >>= 1) {
            unsigned long long o = __shfl_xor(v, m, 64);
            v = o < v ? o : v;
        }
        best[a] = v;
    }
    if (tx == 0) {
        #pragma unroll
        for (int a = 0; a < 4; ++a)
            partial[((split * N_ + n) * HW_) + yq * W_ + i0 + a] = best[a];
    }
}

// ---------------------------------------------------------------------------
// Kernel 3: reduce splits, decode, write outputs (as float32)
// ---------------------------------------------------------------------------
__global__ __launch_bounds__(256)
void finalize_kernel(const unsigned long long* __restrict__ partial,
                     float* __restrict__ out) {
    const int id  = blockIdx.x * 256 + threadIdx.x;   // 0..16383
    const int n   = id >> 12;
    const int pix = id & 4095;
    unsigned long long best = ~0ull;
    #pragma unroll
    for (int sp = 0; sp < SPLITS; ++sp) {
        unsigned long long v = partial[(sp * N_ + n) * HW_ + pix];
        best = v < best ? v : best;
    }
    const unsigned j = (unsigned)(best & 0xffffffffu);
    const float d2 = __uint_as_float((unsigned)(best >> 32));
    out[n * 2 * HW_ + pix]            = (float)(j >> 6);  // idy
    out[n * 2 * HW_ + HW_ + pix]      = (float)(j & 63);  // idx_x
    out[N_ * 2 * HW_ + n * HW_ + pix] = d2;               // nnd
}

// ---------------------------------------------------------------------------
// Fallback: round-1 monolithic kernel (used only if ws is too small)
// ---------------------------------------------------------------------------
__global__ __launch_bounds__(256, 1)
void patchmatch_mono_kernel(const float* __restrict__ s,
                            const float* __restrict__ t,
                            float* __restrict__ out) {
    const int yq  = blockIdx.x;
    const int n   = blockIdx.y;
    const int tid = threadIdx.x;
    const int tx  = tid & 15;
    const int ty  = tid >> 4;
    const int i0  = ty * 4;
    const int jrow = tx >> 3;
    const int jx0  = (tx & 7) * 8;

    __shared__ float qS[C_][3][68];
    __shared__ float tS[C_][4][68];
    __shared__ float pnS[HW_];
    __shared__ float qnS[W_];

    const float* sb = s + n * (C_ * HW_);
    const float* tb = t + n * (C_ * HW_);

    for (int jj = tid; jj < HW_; jj += 256) {
        const int y = jj >> 6, x = jj & 63;
        float acc = 0.f;
        for (int c = 0; c < C_; ++c) {
            const float* tc = tb + c * HW_;
            #pragma unroll
            for (int dy = 0; dy < 3; ++dy) {
                const float* tr = tc + iclamp(y + dy - 1, 0, H_ - 1) * W_;
                #pragma unroll
                for (int dx = 0; dx < 3; ++dx) {
                    float v = tr[iclamp(x + dx - 1, 0, W_ - 1)];
                    acc += v * v;
                }
            }
        }
        pnS[jj] = acc;
    }
    for (int idx = tid; idx < C_ * 3 * 66; idx += 256) {
        const int c   = idx / (3 * 66);
        const int rem = idx - c * (3 * 66);
        const int rr  = rem / 66;
        const int xi  = rem - rr * 66;
        qS[c][rr][xi] = sb[c * HW_ + iclamp(yq + rr - 1, 0, H_ - 1) * W_ +
                           iclamp(xi - 1, 0, W_ - 1)];
    }
    __syncthreads();
    if (tid < W_) {
        float acc = 0.f;
        for (int c = 0; c < C_; ++c)
            #pragma unroll
            for (int dy = 0; dy < 3; ++dy)
                #pragma unroll
                for (int dx = 0; dx < 3; ++dx) {
                    float v = qS[c][dy][tid + dx];
                    acc += v * v;
                }
        qnS[tid] = acc;
    }

    unsigned long long best[4] = {~0ull, ~0ull, ~0ull, ~0ull};
    for (int yt = 0; yt < 32; ++yt) {
        __syncthreads();
        for (int idx = tid; idx < C_ * 4 * 66; idx += 256) {
            const int c   = idx / (4 * 66);
            const int rem = idx - c * (4 * 66);
            const int rr  = rem / 66;
            const int xi  = rem - rr * 66;
            tS[c][rr][xi] = tb[c * HW_ + iclamp(2 * yt + rr - 1, 0, H_ - 1) * W_ +
                               iclamp(xi - 1, 0, W_ - 1)];
        }
        __syncthreads();

        float acc[4][8];
        #pragma unroll
        for (int a = 0; a < 4; ++a)
            #pragma unroll
            for (int b = 0; b < 8; ++b) acc[a][b] = 0.f;

        for (int c = 0; c < C_; ++c) {
            #pragma unroll
            for (int dy = 0; dy < 3; ++dy) {
                float qv[8], tv[12];
                *(float4*)&qv[0] = *(const float4*)&qS[c][dy][i0];
                *(float4*)&qv[4] = *(const float4*)&qS[c][dy][i0 + 4];
                const float* trow = &tS[c][jrow + dy][jx0];
                *(float4*)&tv[0] = *(const float4*)&trow[0];
                *(float4*)&tv[4] = *(const float4*)&trow[4];
                *(float4*)&tv[8] = *(const float4*)&trow[8];
                #pragma unroll
                for (int dx = 0; dx < 3; ++dx)
                    #pragma unroll
                    for (int a = 0; a < 4; ++a)
                        #pragma unroll
                        for (int b = 0; b < 8; ++b)
                            acc[a][b] += qv[a + dx] * tv[b + dx];
            }
        }
        const int rbase = (2 * yt + jrow) * W_ + jx0;
        #pragma unroll
        for (int a = 0; a < 4; ++a) {
            const float qn = qnS[i0 + a];
            #pragma unroll
            for (int b = 0; b < 8; ++b) {
                const int j = rbase + b;
                const float d2 = qn + pnS[j] - 2.f * acc[a][b];
                unsigned long long cand =
                    ((unsigned long long)__float_as_uint(d2) << 32) | (unsigned)j;
                best[a] = cand < best[a] ? cand : best[a];
            }
        }
    }
    #pragma unroll
    for (int a = 0; a < 4; ++a) {
        unsigned long long v = best[a];
        #pragma unroll
        for (int m = 8; m >= 1; m >>= 1) {
            unsigned long long o = __shfl_xor(v, m, 64);
            v = o < v ? o : v;
        }
        best[a] = v;
    }
    if (tx == 0) {
        #pragma unroll
        for (int a = 0; a < 4; ++a) {
            const int x = i0 + a;
            const unsigned j = (unsigned)(best[a] & 0xffffffffu);
            const float d2 = __uint_as_float((unsigned)(best[a] >> 32));
            const int pix = yq * W_ + x;
            out[n * 2 * HW_ + pix]            = (float)(j >> 6);
            out[n * 2 * HW_ + HW_ + pix]      = (float)(j & 63);
            out[N_ * 2 * HW_ + n * HW_ + pix] = d2;
        }
    }
}

extern "C" void kernel_launch(void* const* d_in, const int* in_sizes, int n_in,
                              void* d_out, int out_size, void* d_ws, size_t ws_size,
                              hipStream_t stream) {
    const float* s = (const float*)d_in[0];
    const float* t = (const float*)d_in[1];
    float* out = (float*)d_out;

    // ws layout: pn[4][4096] f32 | qn[4][4096] f32 | partial[4][4][4096] u64
    const size_t need = (size_t)2 * N_ * HW_ * 4 + (size_t)SPLITS * N_ * HW_ * 8;
    if (ws_size < need) {
        dim3 grid(H_, N_);
        patchmatch_mono_kernel<<<grid, 256, 0, stream>>>(s, t, out);
        return;
    }
    float* pn = (float*)d_ws;
    float* qn = pn + N_ * HW_;
    unsigned long long* partial =
        (unsigned long long*)((char*)d_ws + (size_t)2 * N_ * HW_ * 4);

    prep_norms_kernel<<<128, 256, 0, stream>>>(s, t, pn, qn);
    dim3 grid(H_, N_, SPLITS);
    patchmatch_main_kernel<<<grid, 256, 0, stream>>>(s, t, pn, qn, partial);
    finalize_kernel<<<64, 256, 0, stream>>>(partial, out);
}

// Round 3
// 413.794 us; speedup vs baseline: 1.2197x; 1.1343x over previous
//
#include <hip/hip_runtime.h>

// PatchMatch brute-force NN: s,t (4,16,64,64) fp32, patch 3x3 replicate-pad.
// Descriptor dim K = 16*9 = 144. Per batch: 4096 queries vs 4096 targets.
// d2(i,j) = qn_i - 2*cross(i,j) + pn_j, argmin_j per i (ties -> smallest j).
// Outputs (concat flat, ALL FLOAT32): nnf (4,2,64,64) then nnd (4,1,64,64).
//
// R3: R2 structure (prep norms + 4-way j-split main + finalize), but WITHOUT
// the __launch_bounds__ min-wave clamp that forced VGPR=64 and spilled the
// accumulators to scratch (R2: WRITE_SIZE 107 MB/dispatch of spill traffic).
// Compiler free to use ~116 VGPRs -> 4 waves/SIMD, no spills.

#define N_  4
#define C_  16
#define H_  64
#define W_  64
#define HW_ 4096
#define SPLITS 4
#define TILES_PER_SPLIT 8     // 32 j-tiles (of 128 targets) / 4 splits

__device__ __forceinline__ int iclamp(int v, int lo, int hi) {
    return v < lo ? lo : (v > hi ? hi : v);
}

// ---------------------------------------------------------------------------
// Kernel 1: pn[n][4096] from t, qn[n][4096] from s  (32768 threads)
// ---------------------------------------------------------------------------
__global__ __launch_bounds__(256)
void prep_norms_kernel(const float* __restrict__ s,
                       const float* __restrict__ t,
                       float* __restrict__ pn,
                       float* __restrict__ qn) {
    const int gid   = blockIdx.x * 256 + threadIdx.x;   // 0..32767
    const int which = gid >> 14;                        // 0 -> pn(t), 1 -> qn(s)
    const int id    = gid & 16383;
    const int n     = id >> 12;
    const int pix   = id & 4095;
    const int y = pix >> 6, x = pix & 63;
    const float* base = (which ? s : t) + n * (C_ * HW_);
    float acc = 0.f;
    for (int c = 0; c < C_; ++c) {
        const float* bc = base + c * HW_;
        #pragma unroll
        for (int dy = 0; dy < 3; ++dy) {
            const float* br = bc + iclamp(y + dy - 1, 0, H_ - 1) * W_;
            #pragma unroll
            for (int dx = 0; dx < 3; ++dx) {
                float v = br[iclamp(x + dx - 1, 0, W_ - 1)];
                acc += v * v;
            }
        }
    }
    (which ? qn : pn)[id] = acc;
}

// ---------------------------------------------------------------------------
// Kernel 2: main cross/argmin over a j-split; partial best -> ws
// ---------------------------------------------------------------------------
__global__ __launch_bounds__(256)
void patchmatch_main_kernel(const float* __restrict__ s,
                            const float* __restrict__ t,
                            const float* __restrict__ pn_g,
                            const float* __restrict__ qn_g,
                            unsigned long long* __restrict__ partial) {
    const int yq    = blockIdx.x;   // query row
    const int n     = blockIdx.y;   // batch
    const int split = blockIdx.z;   // j-split
    const int tid = threadIdx.x;
    const int tx  = tid & 15;
    const int ty  = tid >> 4;
    const int i0  = ty * 4;          // 4 queries per thread
    const int jrow = tx >> 3;        // which of 2 target rows in the j-tile
    const int jx0  = (tx & 7) * 8;   // 8 targets per thread

    __shared__ float qS[C_][3][68];            // 13056 B
    __shared__ float tS[C_][4][68];            // 17408 B
    __shared__ __align__(16) float pnSl[1024]; //  4096 B (this split's targets)
    __shared__ float qnS[W_];                  //   256 B

    const float* sb = s + n * (C_ * HW_);
    const float* tb = t + n * (C_ * HW_);

    // stage qS (16c x 3 rows x 66 padded cols, stride 68)
    for (int idx = tid; idx < C_ * 3 * 66; idx += 256) {
        const int c   = idx / (3 * 66);
        const int rem = idx - c * (3 * 66);
        const int rr  = rem / 66;
        const int xi  = rem - rr * 66;
        qS[c][rr][xi] = sb[c * HW_ + iclamp(yq + rr - 1, 0, H_ - 1) * W_ +
                           iclamp(xi - 1, 0, W_ - 1)];
    }
    // stage this split's pn slice (rows 16*split .. 16*split+15)
    for (int idx = tid; idx < 1024; idx += 256)
        pnSl[idx] = pn_g[n * HW_ + split * 1024 + idx];
    if (tid < W_) qnS[tid] = qn_g[n * HW_ + yq * W_ + tid];

    unsigned long long best[4] = {~0ull, ~0ull, ~0ull, ~0ull};

    for (int ytl = 0; ytl < TILES_PER_SPLIT; ++ytl) {
        const int yt = split * TILES_PER_SPLIT + ytl;
        __syncthreads();                       // qS ready (iter 0) / tS reuse
        for (int idx = tid; idx < C_ * 4 * 66; idx += 256) {
            const int c   = idx / (4 * 66);
            const int rem = idx - c * (4 * 66);
            const int rr  = rem / 66;
            const int xi  = rem - rr * 66;
            tS[c][rr][xi] = tb[c * HW_ + iclamp(2 * yt + rr - 1, 0, H_ - 1) * W_ +
                               iclamp(xi - 1, 0, W_ - 1)];
        }
        __syncthreads();

        float acc[4][8];
        #pragma unroll
        for (int a = 0; a < 4; ++a)
            #pragma unroll
            for (int b = 0; b < 8; ++b) acc[a][b] = 0.f;

        for (int c = 0; c < C_; ++c) {
            #pragma unroll
            for (int dy = 0; dy < 3; ++dy) {
                float qv[8], tv[12];
                *(float4*)&qv[0] = *(const float4*)&qS[c][dy][i0];
                *(float4*)&qv[4] = *(const float4*)&qS[c][dy][i0 + 4];
                const float* trow = &tS[c][jrow + dy][jx0];
                *(float4*)&tv[0] = *(const float4*)&trow[0];
                *(float4*)&tv[4] = *(const float4*)&trow[4];
                *(float4*)&tv[8] = *(const float4*)&trow[8];
                #pragma unroll
                for (int dx = 0; dx < 3; ++dx)
                    #pragma unroll
                    for (int a = 0; a < 4; ++a)
                        #pragma unroll
                        for (int b = 0; b < 8; ++b)
                            acc[a][b] += qv[a + dx] * tv[b + dx];
            }
        }

        // epilogue: d2 = qn + pn - 2*cross
        const int rbl = (2 * ytl + jrow) * W_ + jx0;   // local in pnSl
        float pnv[8];
        *(float4*)&pnv[0] = *(const float4*)&pnSl[rbl];
        *(float4*)&pnv[4] = *(const float4*)&pnSl[rbl + 4];
        const int jbase = split * 1024 + rbl;          // global j
        #pragma unroll
        for (int a = 0; a < 4; ++a) {
            const float qn = qnS[i0 + a];
            #pragma unroll
            for (int b = 0; b < 8; ++b) {
                const float d2 = qn + pnv[b] - 2.f * acc[a][b];
                unsigned long long cand =
                    ((unsigned long long)__float_as_uint(d2) << 32) |
                    (unsigned)(jbase + b);
                best[a] = cand < best[a] ? cand : best[a];
            }
        }
    }

    // reduce across the 16 tx lanes sharing each query
    #pragma unroll
    for (int a = 0; a < 4; ++a) {
        unsigned long long v = best[a];
        #pragma unroll
        for (int m = 8; m >= 1; m >>= 1) {
            unsigned long long o = __shfl_xor(v, m, 64);
            v = o < v ? o : v;
        }
        best[a] = v;
    }
    if (tx == 0) {
        #pragma unroll
        for (int a = 0; a < 4; ++a)
            partial[((split * N_ + n) * HW_) + yq * W_ + i0 + a] = best[a];
    }
}

// ---------------------------------------------------------------------------
// Kernel 3: reduce splits, decode, write outputs (as float32)
// ---------------------------------------------------------------------------
__global__ __launch_bounds__(256)
void finalize_kernel(const unsigned long long* __restrict__ partial,
                     float* __restrict__ out) {
    const int id  = blockIdx.x * 256 + threadIdx.x;   // 0..16383
    const int n   = id >> 12;
    const int pix = id & 4095;
    unsigned long long best = ~0ull;
    #pragma unroll
    for (int sp = 0; sp < SPLITS; ++sp) {
        unsigned long long v = partial[(sp * N_ + n) * HW_ + pix];
        best = v < best ? v : best;
    }
    const unsigned j = (unsigned)(best & 0xffffffffu);
    const float d2 = __uint_as_float((unsigned)(best >> 32));
    out[n * 2 * HW_ + pix]            = (float)(j >> 6);  // idy
    out[n * 2 * HW_ + HW_ + pix]      = (float)(j & 63);  // idx_x
    out[N_ * 2 * HW_ + n * HW_ + pix] = d2;               // nnd
}

// ---------------------------------------------------------------------------
// Fallback: monolithic kernel (used only if ws is too small)
// ---------------------------------------------------------------------------
__global__ __launch_bounds__(256)
void patchmatch_mono_kernel(const float* __restrict__ s,
                            const float* __restrict__ t,
                            float* __restrict__ out) {
    const int yq  = blockIdx.x;
    const int n   = blockIdx.y;
    const int tid = threadIdx.x;
    const int tx  = tid & 15;
    const int ty  = tid >> 4;
    const int i0  = ty * 4;
    const int jrow = tx >> 3;
    const int jx0  = (tx & 7) * 8;

    __shared__ float qS[C_][3][68];
    __shared__ float tS[C_][4][68];
    __shared__ float pnS[HW_];
    __shared__ float qnS[W_];

    const float* sb = s + n * (C_ * HW_);
    const float* tb = t + n * (C_ * HW_);

    for (int jj = tid; jj < HW_; jj += 256) {
        const int y = jj >> 6, x = jj & 63;
        float acc = 0.f;
        for (int c = 0; c < C_; ++c) {
            const float* tc = tb + c * HW_;
            #pragma unroll
            for (int dy = 0; dy < 3; ++dy) {
                const float* tr = tc + iclamp(y + dy - 1, 0, H_ - 1) * W_;
                #pragma unroll
                for (int dx = 0; dx < 3; ++dx) {
                    float v = tr[iclamp(x + dx - 1, 0, W_ - 1)];
                    acc += v * v;
                }
            }
        }
        pnS[jj] = acc;
    }
    for (int idx = tid; idx < C_ * 3 * 66; idx += 256) {
        const int c   = idx / (3 * 66);
        const int rem = idx - c * (3 * 66);
        const int rr  = rem / 66;
        const int xi  = rem - rr * 66;
        qS[c][rr][xi] = sb[c * HW_ + iclamp(yq + rr - 1, 0, H_ - 1) * W_ +
                           iclamp(xi - 1, 0, W_ - 1)];
    }
    __syncthreads();
    if (tid < W_) {
        float acc = 0.f;
        for (int c = 0; c < C_; ++c)
            #pragma unroll
            for (int dy = 0; dy < 3; ++dy)
                #pragma unroll
                for (int dx = 0; dx < 3; ++dx) {
                    float v = qS[c][dy][tid + dx];
                    acc += v * v;
                }
        qnS[tid] = acc;
    }

    unsigned long long best[4] = {~0ull, ~0ull, ~0ull, ~0ull};
    for (int yt = 0; yt < 32; ++yt) {
        __syncthreads();
        for (int idx = tid; idx < C_ * 4 * 66; idx += 256) {
            const int c   = idx / (4 * 66);
            const int rem = idx - c * (4 * 66);
            const int rr  = rem / 66;
            const int xi  = rem - rr * 66;
            tS[c][rr][xi] = tb[c * HW_ + iclamp(2 * yt + rr - 1, 0, H_ - 1) * W_ +
                               iclamp(xi - 1, 0, W_ - 1)];
        }
        __syncthreads();

        float acc[4][8];
        #pragma unroll
        for (int a = 0; a < 4; ++a)
            #pragma unroll
            for (int b = 0; b < 8; ++b) acc[a][b] = 0.f;

        for (int c = 0; c < C_; ++c) {
            #pragma unroll
            for (int dy = 0; dy < 3; ++dy) {
                float qv[8], tv[12];
                *(float4*)&qv[0] = *(const float4*)&qS[c][dy][i0];
                *(float4*)&qv[4] = *(const float4*)&qS[c][dy][i0 + 4];
                const float* trow = &tS[c][jrow + dy][jx0];
                *(float4*)&tv[0] = *(const float4*)&trow[0];
                *(float4*)&tv[4] = *(const float4*)&trow[4];
                *(float4*)&tv[8] = *(const float4*)&trow[8];
                #pragma unroll
                for (int dx = 0; dx < 3; ++dx)
                    #pragma unroll
                    for (int a = 0; a < 4; ++a)
                        #pragma unroll
                        for (int b = 0; b < 8; ++b)
                            acc[a][b] += qv[a + dx] * tv[b + dx];
            }
        }
        const int rbase = (2 * yt + jrow) * W_ + jx0;
        #pragma unroll
        for (int a = 0; a < 4; ++a) {
            const float qn = qnS[i0 + a];
            #pragma unroll
            for (int b = 0; b < 8; ++b) {
                const int j = rbase + b;
                const float d2 = qn + pnS[j] - 2.f * acc[a][b];
                unsigned long long cand =
                    ((unsigned long long)__float_as_uint(d2) << 32) | (unsigned)j;
                best[a] = cand < best[a] ? cand : best[a];
            }
        }
    }
    #pragma unroll
    for (int a = 0; a < 4; ++a) {
        unsigned long long v = best[a];
        #pragma unroll
        for (int m = 8; m >= 1; m >>= 1) {
            unsigned long long o = __shfl_xor(v, m, 64);
            v = o < v ? o : v;
        }
        best[a] = v;
    }
    if (tx == 0) {
        #pragma unroll
        for (int a = 0; a < 4; ++a) {
            const int x = i0 + a;
            const unsigned j = (unsigned)(best[a] & 0xffffffffu);
            const float d2 = __uint_as_float((unsigned)(best[a] >> 32));
            const int pix = yq * W_ + x;
            out[n * 2 * HW_ + pix]            = (float)(j >> 6);
            out[n * 2 * HW_ + HW_ + pix]      = (float)(j & 63);
            out[N_ * 2 * HW_ + n * HW_ + pix] = d2;
        }
    }
}

extern "C" void kernel_launch(void* const* d_in, const int* in_sizes, int n_in,
                              void* d_out, int out_size, void* d_ws, size_t ws_size,
                              hipStream_t stream) {
    const float* s = (const float*)d_in[0];
    const float* t = (const float*)d_in[1];
    float* out = (float*)d_out;

    // ws layout: pn[4][4096] f32 | qn[4][4096] f32 | partial[4][4][4096] u64
    const size_t need = (size_t)2 * N_ * HW_ * 4 + (size_t)SPLITS * N_ * HW_ * 8;
    if (ws_size < need) {
        dim3 grid(H_, N_);
        patchmatch_mono_kernel<<<grid, 256, 0, stream>>>(s, t, out);
        return;
    }
    float* pn = (float*)d_ws;
    float* qn = pn + N_ * HW_;
    unsigned long long* partial =
        (unsigned long long*)((char*)d_ws + (size_t)2 * N_ * HW_ * 4);

    prep_norms_kernel<<<128, 256, 0, stream>>>(s, t, pn, qn);
    dim3 grid(H_, N_, SPLITS);
    patchmatch_main_kernel<<<grid, 256, 0, stream>>>(s, t, pn, qn, partial);
    finalize_kernel<<<64, 256, 0, stream>>>(partial, out);
}

// Round 4
// 363.290 us; speedup vs baseline: 1.3893x; 1.1390x over previous
//
#include <hip/hip_runtime.h>

// PatchMatch brute-force NN: s,t (4,16,64,64) fp32, patch 3x3 replicate-pad.
// Descriptor dim K = 16*9 = 144. Per batch: 4096 queries vs 4096 targets.
// d2(i,j) = qn_i - 2*cross(i,j) + pn_j, argmin_j per i (ties -> smallest j).
// Outputs (concat flat, ALL FLOAT32): nnf (4,2,64,64) then nnd (4,1,64,64).
//
// R4: leaner inner loop (4q x 16t per thread, 256-target j-tiles: 0.5 B LDS
// per FMA), shift-only vectorized float4 staging, pn moved out of LDS.

#define N_  4
#define C_  16
#define H_  64
#define W_  64
#define HW_ 4096
#define SPLITS 4
#define TILES_PER_SPLIT 4     // 16 j-tiles (of 256 targets) / 4 splits

__device__ __forceinline__ int iclamp(int v, int lo, int hi) {
    return v < lo ? lo : (v > hi ? hi : v);
}

// ---------------------------------------------------------------------------
// Kernel 1: pn[n][4096] from t, qn[n][4096] from s  (32768 threads)
// ---------------------------------------------------------------------------
__global__ __launch_bounds__(256)
void prep_norms_kernel(const float* __restrict__ s,
                       const float* __restrict__ t,
                       float* __restrict__ pn,
                       float* __restrict__ qn) {
    const int gid   = blockIdx.x * 256 + threadIdx.x;   // 0..32767
    const int which = gid >> 14;                        // 0 -> pn(t), 1 -> qn(s)
    const int id    = gid & 16383;
    const int n     = id >> 12;
    const int pix   = id & 4095;
    const int y = pix >> 6, x = pix & 63;
    const float* base = (which ? s : t) + n * (C_ * HW_);
    float acc = 0.f;
    for (int c = 0; c < C_; ++c) {
        const float* bc = base + c * HW_;
        #pragma unroll
        for (int dy = 0; dy < 3; ++dy) {
            const float* br = bc + iclamp(y + dy - 1, 0, H_ - 1) * W_;
            #pragma unroll
            for (int dx = 0; dx < 3; ++dx) {
                float v = br[iclamp(x + dx - 1, 0, W_ - 1)];
                acc += v * v;
            }
        }
    }
    (which ? qn : pn)[id] = acc;
}

// ---------------------------------------------------------------------------
// Kernel 2: main cross/argmin over a j-split; partial best -> ws
// thread map: tx = tid&15 -> target group (jrow = tx>>2 of 4 rows,
//             jx0 = (tx&3)*16 of 16 cols);  ty = tid>>4 -> 4 queries i0=ty*4
// ---------------------------------------------------------------------------
__global__ __launch_bounds__(256)
void patchmatch_main_kernel(const float* __restrict__ s,
                            const float* __restrict__ t,
                            const float* __restrict__ pn_g,
                            const float* __restrict__ qn_g,
                            unsigned long long* __restrict__ partial) {
    const int yq    = blockIdx.x;   // query row
    const int n     = blockIdx.y;   // batch
    const int split = blockIdx.z;   // j-split
    const int tid  = threadIdx.x;
    const int tx   = tid & 15;
    const int ty   = tid >> 4;
    const int i0   = ty * 4;          // 4 queries per thread
    const int jrow = tx >> 2;         // target row within 4-row tile
    const int jx0  = (tx & 3) * 16;   // 16 targets per thread

    // padded x: index xi in [0,65] = global x clamp(xi-1); stride 68 (16B mult)
    __shared__ float qS[C_][3][68];   // 13056 B
    __shared__ float tS[C_][6][68];   // 26112 B
    __shared__ float qnS[W_];         //   256 B   -> total 39424 B, 4 blk/CU

    const float* sb = s + n * (C_ * HW_);
    const float* tb = t + n * (C_ * HW_);

    // ---- stage qS: 3 rows x 16c x 16 float4 segs, shift-only indexing ----
    #pragma unroll
    for (int k = 0; k < 3; ++k) {
        const int id = tid + k * 256;          // 0..767
        const int sg = id & 15;                // float4 segment
        const int c  = (id >> 4) & 15;
        const int r  = id >> 8;                // 0..2
        const int gr = iclamp(yq + r - 1, 0, H_ - 1);
        const float4 v = *(const float4*)&sb[c * HW_ + gr * W_ + sg * 4];
        float* dst = &qS[c][r][1 + sg * 4];
        dst[0] = v.x; dst[1] = v.y; dst[2] = v.z; dst[3] = v.w;
    }
    if (tid < 48) {                            // edges: 16c x 3r
        const int c  = tid & 15;
        const int r  = tid >> 4;
        const int gr = iclamp(yq + r - 1, 0, H_ - 1);
        qS[c][r][0]  = sb[c * HW_ + gr * W_];
        qS[c][r][65] = sb[c * HW_ + gr * W_ + 63];
    }
    if (tid < W_) qnS[tid] = qn_g[n * HW_ + yq * W_ + tid];

    unsigned long long best[4] = {~0ull, ~0ull, ~0ull, ~0ull};

    for (int ytl = 0; ytl < TILES_PER_SPLIT; ++ytl) {
        const int yt = split * TILES_PER_SPLIT + ytl;   // 4-row tile id 0..15
        __syncthreads();                   // qS ready (iter 0) / tS reuse
        // ---- stage tS: 6 rows x 16c x 16 float4 segs ----
        #pragma unroll
        for (int k = 0; k < 6; ++k) {
            const int id = tid + k * 256;      // 0..1535
            const int sg = id & 15;
            const int c  = (id >> 4) & 15;
            const int r  = id >> 8;            // 0..5
            const int gr = iclamp(4 * yt + r - 1, 0, H_ - 1);
            const float4 v = *(const float4*)&tb[c * HW_ + gr * W_ + sg * 4];
            float* dst = &tS[c][r][1 + sg * 4];
            dst[0] = v.x; dst[1] = v.y; dst[2] = v.z; dst[3] = v.w;
        }
        if (tid < 96) {                        // edges: 16c x 6r
            const int c  = tid & 15;
            const int r  = tid >> 4;
            const int gr = iclamp(4 * yt + r - 1, 0, H_ - 1);
            tS[c][r][0]  = tb[c * HW_ + gr * W_];
            tS[c][r][65] = tb[c * HW_ + gr * W_ + 63];
        }
        __syncthreads();

        float acc[4][16];
        #pragma unroll
        for (int a = 0; a < 4; ++a)
            #pragma unroll
            for (int b = 0; b < 16; ++b) acc[a][b] = 0.f;

        for (int c = 0; c < C_; ++c) {
            #pragma unroll
            for (int dy = 0; dy < 3; ++dy) {
                float qv[6], tv[18];
                *(float4*)&qv[0] = *(const float4*)&qS[c][dy][i0];
                *(float2*)&qv[4] = *(const float2*)&qS[c][dy][i0 + 4];
                const float* trow = &tS[c][jrow + dy][jx0];
                *(float4*)&tv[0]  = *(const float4*)&trow[0];
                *(float4*)&tv[4]  = *(const float4*)&trow[4];
                *(float4*)&tv[8]  = *(const float4*)&trow[8];
                *(float4*)&tv[12] = *(const float4*)&trow[12];
                *(float2*)&tv[16] = *(const float2*)&trow[16];
                #pragma unroll
                for (int dx = 0; dx < 3; ++dx)
                    #pragma unroll
                    for (int a = 0; a < 4; ++a)
                        #pragma unroll
                        for (int b = 0; b < 16; ++b)
                            acc[a][b] += qv[a + dx] * tv[b + dx];
            }
        }

        // epilogue: d2 = qn + pn - 2*cross (pn from L2-resident global)
        const int jbase = yt * 256 + jrow * W_ + jx0;   // global j of tv[0]
        float pnv[16];
        const float* png = &pn_g[n * HW_ + jbase];
        *(float4*)&pnv[0]  = *(const float4*)&png[0];
        *(float4*)&pnv[4]  = *(const float4*)&png[4];
        *(float4*)&pnv[8]  = *(const float4*)&png[8];
        *(float4*)&pnv[12] = *(const float4*)&png[12];
        #pragma unroll
        for (int a = 0; a < 4; ++a) {
            const float qn = qnS[i0 + a];
            #pragma unroll
            for (int b = 0; b < 16; ++b) {
                const float d2 = qn + pnv[b] - 2.f * acc[a][b];
                unsigned long long cand =
                    ((unsigned long long)__float_as_uint(d2) << 32) |
                    (unsigned)(jbase + b);
                best[a] = cand < best[a] ? cand : best[a];
            }
        }
    }

    // reduce across the 16 tx lanes sharing each query
    #pragma unroll
    for (int a = 0; a < 4; ++a) {
        unsigned long long v = best[a];
        #pragma unroll
        for (int m = 8; m >= 1; m >>= 1) {
            unsigned long long o = __shfl_xor(v, m, 64);
            v = o < v ? o : v;
        }
        best[a] = v;
    }
    if (tx == 0) {
        #pragma unroll
        for (int a = 0; a < 4; ++a)
            partial[((split * N_ + n) * HW_) + yq * W_ + i0 + a] = best[a];
    }
}

// ---------------------------------------------------------------------------
// Kernel 3: reduce splits, decode, write outputs (as float32)
// ---------------------------------------------------------------------------
__global__ __launch_bounds__(256)
void finalize_kernel(const unsigned long long* __restrict__ partial,
                     float* __restrict__ out) {
    const int id  = blockIdx.x * 256 + threadIdx.x;   // 0..16383
    const int n   = id >> 12;
    const int pix = id & 4095;
    unsigned long long best = ~0ull;
    #pragma unroll
    for (int sp = 0; sp < SPLITS; ++sp) {
        unsigned long long v = partial[(sp * N_ + n) * HW_ + pix];
        best = v < best ? v : best;
    }
    const unsigned j = (unsigned)(best & 0xffffffffu);
    const float d2 = __uint_as_float((unsigned)(best >> 32));
    out[n * 2 * HW_ + pix]            = (float)(j >> 6);  // idy
    out[n * 2 * HW_ + HW_ + pix]      = (float)(j & 63);  // idx_x
    out[N_ * 2 * HW_ + n * HW_ + pix] = d2;               // nnd
}

// ---------------------------------------------------------------------------
// Fallback: monolithic kernel (used only if ws is too small)
// ---------------------------------------------------------------------------
__global__ __launch_bounds__(256)
void patchmatch_mono_kernel(const float* __restrict__ s,
                            const float* __restrict__ t,
                            float* __restrict__ out) {
    const int yq  = blockIdx.x;
    const int n   = blockIdx.y;
    const int tid = threadIdx.x;
    const int tx  = tid & 15;
    const int ty  = tid >> 4;
    const int i0  = ty * 4;
    const int jrow = tx >> 3;
    const int jx0  = (tx & 7) * 8;

    __shared__ float qS[C_][3][68];
    __shared__ float tS[C_][4][68];
    __shared__ float pnS[HW_];
    __shared__ float qnS[W_];

    const float* sb = s + n * (C_ * HW_);
    const float* tb = t + n * (C_ * HW_);

    for (int jj = tid; jj < HW_; jj += 256) {
        const int y = jj >> 6, x = jj & 63;
        float acc = 0.f;
        for (int c = 0; c < C_; ++c) {
            const float* tc = tb + c * HW_;
            #pragma unroll
            for (int dy = 0; dy < 3; ++dy) {
                const float* tr = tc + iclamp(y + dy - 1, 0, H_ - 1) * W_;
                #pragma unroll
                for (int dx = 0; dx < 3; ++dx) {
                    float v = tr[iclamp(x + dx - 1, 0, W_ - 1)];
                    acc += v * v;
                }
            }
        }
        pnS[jj] = acc;
    }
    for (int idx = tid; idx < C_ * 3 * 66; idx += 256) {
        const int c   = idx / (3 * 66);
        const int rem = idx - c * (3 * 66);
        const int rr  = rem / 66;
        const int xi  = rem - rr * 66;
        qS[c][rr][xi] = sb[c * HW_ + iclamp(yq + rr - 1, 0, H_ - 1) * W_ +
                           iclamp(xi - 1, 0, W_ - 1)];
    }
    __syncthreads();
    if (tid < W_) {
        float acc = 0.f;
        for (int c = 0; c < C_; ++c)
            #pragma unroll
            for (int dy = 0; dy < 3; ++dy)
                #pragma unroll
                for (int dx = 0; dx < 3; ++dx) {
                    float v = qS[c][dy][tid + dx];
                    acc += v * v;
                }
        qnS[tid] = acc;
    }

    unsigned long long best[4] = {~0ull, ~0ull, ~0ull, ~0ull};
    for (int yt = 0; yt < 32; ++yt) {
        __syncthreads();
        for (int idx = tid; idx < C_ * 4 * 66; idx += 256) {
            const int c   = idx / (4 * 66);
            const int rem = idx - c * (4 * 66);
            const int rr  = rem / 66;
            const int xi  = rem - rr * 66;
            tS[c][rr][xi] = tb[c * HW_ + iclamp(2 * yt + rr - 1, 0, H_ - 1) * W_ +
                               iclamp(xi - 1, 0, W_ - 1)];
        }
        __syncthreads();

        float acc[4][8];
        #pragma unroll
        for (int a = 0; a < 4; ++a)
            #pragma unroll
            for (int b = 0; b < 8; ++b) acc[a][b] = 0.f;

        for (int c = 0; c < C_; ++c) {
            #pragma unroll
            for (int dy = 0; dy < 3; ++dy) {
                float qv[8], tv[12];
                *(float4*)&qv[0] = *(const float4*)&qS[c][dy][i0];
                *(float4*)&qv[4] = *(const float4*)&qS[c][dy][i0 + 4];
                const float* trow = &tS[c][jrow + dy][jx0];
                *(float4*)&tv[0] = *(const float4*)&trow[0];
                *(float4*)&tv[4] = *(const float4*)&trow[4];
                *(float4*)&tv[8] = *(const float4*)&trow[8];
                #pragma unroll
                for (int dx = 0; dx < 3; ++dx)
                    #pragma unroll
                    for (int a = 0; a < 4; ++a)
                        #pragma unroll
                        for (int b = 0; b < 8; ++b)
                            acc[a][b] += qv[a + dx] * tv[b + dx];
            }
        }
        const int rbase = (2 * yt + jrow) * W_ + jx0;
        #pragma unroll
        for (int a = 0; a < 4; ++a) {
            const float qn = qnS[i0 + a];
            #pragma unroll
            for (int b = 0; b < 8; ++b) {
                const int j = rbase + b;
                const float d2 = qn + pnS[j] - 2.f * acc[a][b];
                unsigned long long cand =
                    ((unsigned long long)__float_as_uint(d2) << 32) | (unsigned)j;
                best[a] = cand < best[a] ? cand : best[a];
            }
        }
    }
    #pragma unroll
    for (int a = 0; a < 4; ++a) {
        unsigned long long v = best[a];
        #pragma unroll
        for (int m = 8; m >= 1; m >>= 1) {
            unsigned long long o = __shfl_xor(v, m, 64);
            v = o < v ? o : v;
        }
        best[a] = v;
    }
    if (tx == 0) {
        #pragma unroll
        for (int a = 0; a < 4; ++a) {
            const int x = i0 + a;
            const unsigned j = (unsigned)(best[a] & 0xffffffffu);
            const float d2 = __uint_as_float((unsigned)(best[a] >> 32));
            const int pix = yq * W_ + x;
            out[n * 2 * HW_ + pix]            = (float)(j >> 6);
            out[n * 2 * HW_ + HW_ + pix]      = (float)(j & 63);
            out[N_ * 2 * HW_ + n * HW_ + pix] = d2;
        }
    }
}

extern "C" void kernel_launch(void* const* d_in, const int* in_sizes, int n_in,
                              void* d_out, int out_size, void* d_ws, size_t ws_size,
                              hipStream_t stream) {
    const float* s = (const float*)d_in[0];
    const float* t = (const float*)d_in[1];
    float* out = (float*)d_out;

    // ws layout: pn[4][4096] f32 | qn[4][4096] f32 | partial[4][4][4096] u64
    const size_t need = (size_t)2 * N_ * HW_ * 4 + (size_t)SPLITS * N_ * HW_ * 8;
    if (ws_size < need) {
        dim3 grid(H_, N_);
        patchmatch_mono_kernel<<<grid, 256, 0, stream>>>(s, t, out);
        return;
    }
    float* pn = (float*)d_ws;
    float* qn = pn + N_ * HW_;
    unsigned long long* partial =
        (unsigned long long*)((char*)d_ws + (size_t)2 * N_ * HW_ * 4);

    prep_norms_kernel<<<128, 256, 0, stream>>>(s, t, pn, qn);
    dim3 grid(H_, N_, SPLITS);
    patchmatch_main_kernel<<<grid, 256, 0, stream>>>(s, t, pn, qn, partial);
    finalize_kernel<<<64, 256, 0, stream>>>(partial, out);
}